// Round 9
// baseline (441.059 us; speedup 1.0000x reference)
//
#include <hip/hip_runtime.h>
#include <hip/hip_bf16.h>

#define SLOPE 0.2f

// ---------- init: zero deg + detect edge-index dtype ----------
__global__ __launch_bounds__(256) void k_init(int* __restrict__ deg, int n,
                                              const int* __restrict__ ei,
                                              int* __restrict__ flag) {
    int i = blockIdx.x * 256 + threadIdx.x;
    if (i < n) deg[i] = 0;
    if (blockIdx.x == 0) {
        __shared__ int cnt;
        if (threadIdx.x == 0) cnt = 0;
        __syncthreads();
        int z = 0;
        for (int k = threadIdx.x; k < 4096; k += 256)
            if ((k & 1) && ei[k] == 0) z++;
        atomicAdd(&cnt, z);
        __syncthreads();
        if (threadIdx.x == 0) *flag = (cnt > 1024) ? 1 : 0;
    }
}

__device__ inline int esrc_at(const int* ei, int E, int f, int e) {
    return f ? ei[2 * e] : ei[e];
}
__device__ inline int edst_at(const int* ei, int E, int f, int e) {
    return f ? ei[2 * (E + e)] : ei[E + e];
}

// ---------- CSR build ----------

__global__ __launch_bounds__(256) void k_hist(const int* __restrict__ ei, int E,
                                              const int* __restrict__ flag,
                                              int* __restrict__ deg,
                                              int* __restrict__ rank) {
    int e = blockIdx.x * 256 + threadIdx.x;
    if (e < E) rank[e] = atomicAdd(&deg[edst_at(ei, E, *flag, e)], 1);
}

__global__ __launch_bounds__(256) void k_scan_part(const int* __restrict__ deg, int n,
                                                   int* __restrict__ parts) {
    __shared__ int s[256];
    int base = blockIdx.x * 1024;
    int sum = 0;
    for (int j = threadIdx.x; j < 1024; j += 256) {
        int i = base + j;
        sum += (i < n) ? deg[i] : 0;
    }
    s[threadIdx.x] = sum;
    __syncthreads();
    for (int off = 128; off > 0; off >>= 1) {
        if (threadIdx.x < off) s[threadIdx.x] += s[threadIdx.x + off];
        __syncthreads();
    }
    if (threadIdx.x == 0) parts[blockIdx.x] = s[0];
}

__global__ __launch_bounds__(256) void k_scan_final(const int* __restrict__ deg, int n,
                                                    const int* __restrict__ parts,
                                                    int NB, int* __restrict__ rowp) {
    __shared__ int sp[1024];
    __shared__ int s[256];
    int t = threadIdx.x;
    for (int j = t; j < 1024; j += 256) sp[j] = (j < NB) ? parts[j] : 0;
    __syncthreads();
    for (int off = 1; off < 1024; off <<= 1) {
        int v[4];
        for (int c = 0; c < 4; ++c) {
            int j = t + c * 256;
            v[c] = (j >= off) ? sp[j - off] : 0;
        }
        __syncthreads();
        for (int c = 0; c < 4; ++c) sp[t + c * 256] += v[c];
        __syncthreads();
    }
    int b = blockIdx.x;
    int chunk_off = (b == 0) ? 0 : sp[b - 1];
    if (b == 0 && t == 0) rowp[n] = sp[NB - 1];
    int base = b * 1024 + t * 4;
    int v0 = (base + 0 < n) ? deg[base + 0] : 0;
    int v1 = (base + 1 < n) ? deg[base + 1] : 0;
    int v2 = (base + 2 < n) ? deg[base + 2] : 0;
    int v3 = (base + 3 < n) ? deg[base + 3] : 0;
    int mysum = v0 + v1 + v2 + v3;
    s[t] = mysum;
    __syncthreads();
    for (int off = 1; off < 256; off <<= 1) {
        int add = (t >= off) ? s[t - off] : 0;
        __syncthreads();
        s[t] += add;
        __syncthreads();
    }
    int excl = chunk_off + s[t] - mysum;
    if (base + 0 < n) rowp[base + 0] = excl;
    if (base + 1 < n) rowp[base + 1] = excl + v0;
    if (base + 2 < n) rowp[base + 2] = excl + v0 + v1;
    if (base + 3 < n) rowp[base + 3] = excl + v0 + v1 + v2;
}

// ---------- dtype helpers ----------

__device__ inline void storef(float* p, size_t i, float v) { p[i] = v; }
__device__ inline void storef(__hip_bfloat16* p, size_t i, float v) {
    p[i] = __float2bfloat16(v);
}

__device__ inline void load8(const float* p, size_t row, int q, float v[8]) {
    const float4* b = reinterpret_cast<const float4*>(p + row * 64);
    float4 x = b[q * 2], y = b[q * 2 + 1];
    v[0] = x.x; v[1] = x.y; v[2] = x.z; v[3] = x.w;
    v[4] = y.x; v[5] = y.y; v[6] = y.z; v[7] = y.w;
}
__device__ inline void load8(const __hip_bfloat16* p, size_t row, int q, float v[8]) {
    uint4 u = reinterpret_cast<const uint4*>(p + row * 64)[q];
    v[0] = __uint_as_float(u.x << 16);
    v[1] = __uint_as_float(u.x & 0xffff0000u);
    v[2] = __uint_as_float(u.y << 16);
    v[3] = __uint_as_float(u.y & 0xffff0000u);
    v[4] = __uint_as_float(u.z << 16);
    v[5] = __uint_as_float(u.z & 0xffff0000u);
    v[6] = __uint_as_float(u.w << 16);
    v[7] = __uint_as_float(u.w & 0xffff0000u);
}

// ---------- lin2 body: 4 rows per wave, W staged in LDS, W-bytes reused x4 ----------
template <typename ST, typename SR>
__device__ __forceinline__ void lin2_body(const float* __restrict__ x,
                                          const float* __restrict__ Wl,
                                          const float* __restrict__ bl,
                                          const float* __restrict__ Wr,
                                          const float* __restrict__ br,
                                          ST* __restrict__ xl,
                                          SR* __restrict__ xr, int n,
                                          int bid, int nblocks) {
    __shared__ float sWl[4096], sWr[4096], sbl[64], sbr[64];
    int t = threadIdx.x;
    for (int k = t; k < 4096; k += 256) {
        sWl[k] = Wl[k];
        sWr[k] = Wr[k];
    }
    if (t < 64) {
        sbl[t] = bl[t];
        sbr[t] = br[t];
    }
    __syncthreads();
    int lane = t & 63;
    int wv = t >> 6;
    int nquads = (n + 3) >> 2;
    for (int qd = bid * 4 + wv; qd < nquads; qd += nblocks * 4) {
        int row0 = qd << 2;
        bool full = (row0 + 4 <= n);
        float al[4], ar[4];
#pragma unroll
        for (int r = 0; r < 4; ++r) {
            al[r] = sbl[lane];
            ar[r] = sbr[lane];
        }
        const float* xp = x + (size_t)row0 * 64;
#pragma unroll
        for (int k4 = 0; k4 < 16; ++k4) {
            float4 xv[4];
#pragma unroll
            for (int r = 0; r < 4; ++r) {
                if (full || row0 + r < n)
                    xv[r] = *reinterpret_cast<const float4*>(xp + (size_t)r * 64 + k4 * 4);
                else
                    xv[r] = make_float4(0.f, 0.f, 0.f, 0.f);
            }
            int kb = k4 << 2;
            float wl0 = sWl[((kb + 0) << 6) + lane], wr0 = sWr[((kb + 0) << 6) + lane];
            float wl1 = sWl[((kb + 1) << 6) + lane], wr1 = sWr[((kb + 1) << 6) + lane];
            float wl2 = sWl[((kb + 2) << 6) + lane], wr2 = sWr[((kb + 2) << 6) + lane];
            float wl3 = sWl[((kb + 3) << 6) + lane], wr3 = sWr[((kb + 3) << 6) + lane];
#pragma unroll
            for (int r = 0; r < 4; ++r) {
                al[r] = fmaf(xv[r].x, wl0, al[r]);
                ar[r] = fmaf(xv[r].x, wr0, ar[r]);
                al[r] = fmaf(xv[r].y, wl1, al[r]);
                ar[r] = fmaf(xv[r].y, wr1, ar[r]);
                al[r] = fmaf(xv[r].z, wl2, al[r]);
                ar[r] = fmaf(xv[r].z, wr2, ar[r]);
                al[r] = fmaf(xv[r].w, wl3, al[r]);
                ar[r] = fmaf(xv[r].w, wr3, ar[r]);
            }
        }
#pragma unroll
        for (int r = 0; r < 4; ++r) {
            if (full || row0 + r < n) {
                storef(xl, (size_t)(row0 + r) * 64 + lane, al[r]);
                storef(xr, (size_t)(row0 + r) * 64 + lane, ar[r]);
            }
        }
    }
}

template <typename ST, typename SR>
__global__ __launch_bounds__(256) void k_lin2(const float* __restrict__ x,
                                              const float* __restrict__ Wl,
                                              const float* __restrict__ bl,
                                              const float* __restrict__ Wr,
                                              const float* __restrict__ br,
                                              ST* __restrict__ xl,
                                              SR* __restrict__ xr, int n) {
    lin2_body<ST, SR>(x, Wl, bl, Wr, br, xl, xr, n, blockIdx.x, gridDim.x);
}

// fused: independent scatter + lin2 layer-0, interleaved block mapping so both
// populations co-reside on CUs (scatter = scattered-store latency, lin2 = LDS/FMA)
template <typename ST, typename SR, typename IT>
__global__ __launch_bounds__(256) void k_scatter_lin2(
    const int* __restrict__ ei, int E, const int* __restrict__ flag,
    const int* __restrict__ rowp, const int* __restrict__ rank,
    IT* __restrict__ ssrc, const float* __restrict__ x,
    const float* __restrict__ Wl, const float* __restrict__ bl,
    const float* __restrict__ Wr, const float* __restrict__ br,
    ST* __restrict__ xl, SR* __restrict__ xr, int n, int lin_blocks,
    int scat_blocks) {
    int bid = blockIdx.x;
    int m = lin_blocks < scat_blocks ? lin_blocks : scat_blocks;
    int m2 = 2 * m;
    bool is_lin;
    int id;
    if (bid < m2) {
        is_lin = !(bid & 1);
        id = bid >> 1;
    } else {
        is_lin = (lin_blocks > m);
        id = m + (bid - m2);
    }
    if (is_lin) {
        lin2_body<ST, SR>(x, Wl, bl, Wr, br, xl, xr, n, id, lin_blocks);
    } else {
        int e = id * 256 + threadIdx.x;
        if (e < E) {
            int f = *flag;
            int i = edst_at(ei, E, f, e);
            ssrc[rowp[i] + rank[e]] = (IT)esrc_at(ei, E, f, e);
        }
    }
}

// ---------- gat: one wave per node; 8 groups of 8 lanes ----------
template <typename ST, typename SR, typename IT>
__global__ __launch_bounds__(256) void k_gat(const ST* __restrict__ xl,
                                             const SR* __restrict__ xr,
                                             const int* __restrict__ rowp,
                                             const IT* __restrict__ ssrc,
                                             const float* __restrict__ att,
                                             const float* __restrict__ bias,
                                             float* __restrict__ out, int n) {
    int wid = (blockIdx.x * 256 + threadIdx.x) >> 6;
    if (wid >= n) return;
    int lane = threadIdx.x & 63;
    int g = lane >> 3;
    int q = lane & 7;
    float a[8], r[8];
    load8(att, 0, q, a);
    load8(xr, (size_t)wid, q, r);
    int beg = rowp[wid], end = rowp[wid + 1];
    float m = -3.4e38f, denom = 0.f;
    float acc[8] = {0.f, 0.f, 0.f, 0.f, 0.f, 0.f, 0.f, 0.f};
    for (int e = beg; e < end; e += 8) {
        int rem = end - e;
        bool valid = (g < rem);
        int idx = e + (valid ? g : rem - 1);
        int s = (int)ssrc[idx];
        float v[8];
        load8(xl, (size_t)s, q, v);
        float l = 0.f;
#pragma unroll
        for (int j = 0; j < 8; ++j) {
            float tj = v[j] + r[j];
            tj = tj > 0.f ? tj : SLOPE * tj;
            l = fmaf(a[j], tj, l);
        }
        l += __shfl_xor(l, 1);
        l += __shfl_xor(l, 2);
        l += __shfl_xor(l, 4);
        float mnew = valid ? fmaxf(m, l) : m;
        float sc = __expf(m - mnew);
        float p = valid ? __expf(l - mnew) : 0.f;
        denom = denom * sc + p;
#pragma unroll
        for (int j = 0; j < 8; ++j) acc[j] = fmaf(acc[j], sc, p * v[j]);
        m = mnew;
    }
    float mt = m;
    mt = fmaxf(mt, __shfl_xor(mt, 8));
    mt = fmaxf(mt, __shfl_xor(mt, 16));
    mt = fmaxf(mt, __shfl_xor(mt, 32));
    float sc = __expf(m - mt);
    denom *= sc;
    denom += __shfl_xor(denom, 8);
    denom += __shfl_xor(denom, 16);
    denom += __shfl_xor(denom, 32);
#pragma unroll
    for (int j = 0; j < 8; ++j) {
        acc[j] *= sc;
        acc[j] += __shfl_xor(acc[j], 8);
        acc[j] += __shfl_xor(acc[j], 16);
        acc[j] += __shfl_xor(acc[j], 32);
    }
    if (g == 0) {
        float b[8];
        load8(bias, 0, q, b);
        float inv = 1.f / denom;
        float o[8];
#pragma unroll
        for (int j = 0; j < 8; ++j) {
            float oj = acc[j] * inv + b[j];
            o[j] = 0.5f * oj * (1.0f + erff(oj * 0.70710678118654752f));
        }
        float4* ob = reinterpret_cast<float4*>(out + (size_t)wid * 64);
        ob[q * 2] = make_float4(o[0], o[1], o[2], o[3]);
        ob[q * 2 + 1] = make_float4(o[4], o[5], o[6], o[7]);
    }
}

// ---------- launch ----------

template <typename ST, typename SR, typename IT>
static void run_all(const int* ei, int E, const int* flag, const int* rowp,
                    const int* rank, IT* ssrc, const float* x0, const float* Wl,
                    const float* bl, const float* Wr, const float* br,
                    const float* att, const float* bias, ST* xl, SR* xr,
                    float* xout, int N, hipStream_t stream) {
    int gat_grid = (N + 3) / 4;
    int neb = (E + 255) / 256;
    const int lin_blocks = 2048;
    // layer 0: scatter fused with lin2
    k_scatter_lin2<ST, SR, IT><<<lin_blocks + neb, 256, 0, stream>>>(
        ei, E, flag, rowp, rank, ssrc, x0, Wl, bl, Wr, br, xl, xr, N,
        lin_blocks, neb);
    k_gat<ST, SR, IT><<<gat_grid, 256, 0, stream>>>(xl, xr, rowp, ssrc, att,
                                                    bias, xout, N);
    for (int l = 1; l < 3; ++l) {
        k_lin2<ST, SR><<<lin_blocks, 256, 0, stream>>>(
            xout, Wl + (size_t)l * 4096, bl + (size_t)l * 64,
            Wr + (size_t)l * 4096, br + (size_t)l * 64, xl, xr, N);
        k_gat<ST, SR, IT><<<gat_grid, 256, 0, stream>>>(xl, xr, rowp, ssrc,
                                                        att + (size_t)l * 64,
                                                        bias + (size_t)l * 64,
                                                        xout, N);
    }
}

extern "C" void kernel_launch(void* const* d_in, const int* in_sizes, int n_in,
                              void* d_out, int out_size, void* d_ws, size_t ws_size,
                              hipStream_t stream) {
    (void)n_in;
    (void)out_size;
    const float* x0 = (const float*)d_in[0];
    const int* ei = (const int*)d_in[1];
    const float* Wl = (const float*)d_in[2];
    const float* bl = (const float*)d_in[3];
    const float* Wr = (const float*)d_in[4];
    const float* br = (const float*)d_in[5];
    const float* att = (const float*)d_in[6];
    const float* bias = (const float*)d_in[7];

    int N = in_sizes[0] / 64;
    int E = in_sizes[1] / 2;
    size_t ND = (size_t)N * 64;

    char* w = (char*)d_ws;
    int* flag = (int*)w;       w += 256;
    int* parts = (int*)w;      w += 4096;
    int* rowp = (int*)w;       w += ((size_t)N + 8) * 4;
    int* deg = (int*)w;        w += ((size_t)N + 8) * 4;
    int* rank = (int*)w;       w += ((size_t)E + 8) * 4;
    unsigned short* ssrc16 = (unsigned short*)w;
    int* ssrc32 = (int*)w;     w += ((size_t)E + 8) * 4;
    size_t head = (size_t)(w - (char*)d_ws);

    bool big = (ws_size >= head + ND * 2 + ND * 4 + 4096);
    bool small_ids = (N <= 65535);

    int NB = (N + 1023) / 1024;
    int neb = (E + 255) / 256;
    int nzb = (N + 255) / 256;

    k_init<<<nzb, 256, 0, stream>>>(deg, N, ei, flag);
    k_hist<<<neb, 256, 0, stream>>>(ei, E, flag, deg, rank);
    k_scan_part<<<NB, 256, 0, stream>>>(deg, N, parts);
    k_scan_final<<<NB, 256, 0, stream>>>(deg, N, parts, NB, rowp);

    float* xout = (float*)d_out;
    if (big) {
        __hip_bfloat16* xl = (__hip_bfloat16*)w;
        float* xr = (float*)(w + ND * 2);
        if (small_ids)
            run_all<__hip_bfloat16, float, unsigned short>(
                ei, E, flag, rowp, rank, ssrc16, x0, Wl, bl, Wr, br, att, bias,
                xl, xr, xout, N, stream);
        else
            run_all<__hip_bfloat16, float, int>(
                ei, E, flag, rowp, rank, ssrc32, x0, Wl, bl, Wr, br, att, bias,
                xl, xr, xout, N, stream);
    } else {
        __hip_bfloat16* xl = (__hip_bfloat16*)w;
        __hip_bfloat16* xr = xl + ND;
        if (small_ids)
            run_all<__hip_bfloat16, __hip_bfloat16, unsigned short>(
                ei, E, flag, rowp, rank, ssrc16, x0, Wl, bl, Wr, br, att, bias,
                xl, xr, xout, N, stream);
        else
            run_all<__hip_bfloat16, __hip_bfloat16, int>(
                ei, E, flag, rowp, rank, ssrc32, x0, Wl, bl, Wr, br, att, bias,
                xl, xr, xout, N, stream);
    }
}

// Round 10
// 358.325 us; speedup vs baseline: 1.2309x; 1.2309x over previous
//
#include <hip/hip_runtime.h>
#include <hip/hip_bf16.h>

#define SLOPE 0.2f

// ---------- init: zero deg + detect edge-index dtype ----------
__global__ __launch_bounds__(256) void k_init(int* __restrict__ deg, int n,
                                              const int* __restrict__ ei,
                                              int* __restrict__ flag) {
    int i = blockIdx.x * 256 + threadIdx.x;
    if (i < n) deg[i] = 0;
    if (blockIdx.x == 0) {
        __shared__ int cnt;
        if (threadIdx.x == 0) cnt = 0;
        __syncthreads();
        int z = 0;
        for (int k = threadIdx.x; k < 4096; k += 256)
            if ((k & 1) && ei[k] == 0) z++;
        atomicAdd(&cnt, z);
        __syncthreads();
        if (threadIdx.x == 0) *flag = (cnt > 1024) ? 1 : 0;
    }
}

__device__ inline int esrc_at(const int* ei, int E, int f, int e) {
    return f ? ei[2 * e] : ei[e];
}
__device__ inline int edst_at(const int* ei, int E, int f, int e) {
    return f ? ei[2 * (E + e)] : ei[E + e];
}

// ---------- CSR build ----------

__global__ __launch_bounds__(256) void k_hist(const int* __restrict__ ei, int E,
                                              const int* __restrict__ flag,
                                              int* __restrict__ deg,
                                              int* __restrict__ rank) {
    int e = blockIdx.x * 256 + threadIdx.x;
    if (e < E) rank[e] = atomicAdd(&deg[edst_at(ei, E, *flag, e)], 1);
}

__global__ __launch_bounds__(256) void k_scan_part(const int* __restrict__ deg, int n,
                                                   int* __restrict__ parts) {
    __shared__ int s[256];
    int base = blockIdx.x * 1024;
    int sum = 0;
    for (int j = threadIdx.x; j < 1024; j += 256) {
        int i = base + j;
        sum += (i < n) ? deg[i] : 0;
    }
    s[threadIdx.x] = sum;
    __syncthreads();
    for (int off = 128; off > 0; off >>= 1) {
        if (threadIdx.x < off) s[threadIdx.x] += s[threadIdx.x + off];
        __syncthreads();
    }
    if (threadIdx.x == 0) parts[blockIdx.x] = s[0];
}

__global__ __launch_bounds__(256) void k_scan_final(const int* __restrict__ deg, int n,
                                                    const int* __restrict__ parts,
                                                    int NB, int* __restrict__ rowp) {
    __shared__ int sp[1024];
    __shared__ int s[256];
    int t = threadIdx.x;
    for (int j = t; j < 1024; j += 256) sp[j] = (j < NB) ? parts[j] : 0;
    __syncthreads();
    for (int off = 1; off < 1024; off <<= 1) {
        int v[4];
        for (int c = 0; c < 4; ++c) {
            int j = t + c * 256;
            v[c] = (j >= off) ? sp[j - off] : 0;
        }
        __syncthreads();
        for (int c = 0; c < 4; ++c) sp[t + c * 256] += v[c];
        __syncthreads();
    }
    int b = blockIdx.x;
    int chunk_off = (b == 0) ? 0 : sp[b - 1];
    if (b == 0 && t == 0) rowp[n] = sp[NB - 1];
    int base = b * 1024 + t * 4;
    int v0 = (base + 0 < n) ? deg[base + 0] : 0;
    int v1 = (base + 1 < n) ? deg[base + 1] : 0;
    int v2 = (base + 2 < n) ? deg[base + 2] : 0;
    int v3 = (base + 3 < n) ? deg[base + 3] : 0;
    int mysum = v0 + v1 + v2 + v3;
    s[t] = mysum;
    __syncthreads();
    for (int off = 1; off < 256; off <<= 1) {
        int add = (t >= off) ? s[t - off] : 0;
        __syncthreads();
        s[t] += add;
        __syncthreads();
    }
    int excl = chunk_off + s[t] - mysum;
    if (base + 0 < n) rowp[base + 0] = excl;
    if (base + 1 < n) rowp[base + 1] = excl + v0;
    if (base + 2 < n) rowp[base + 2] = excl + v0 + v1;
    if (base + 3 < n) rowp[base + 3] = excl + v0 + v1 + v2;
}

// atomic-free scatter: position = rowp[dst] + rank[e]
template <typename IT>
__global__ __launch_bounds__(256) void k_scatter(const int* __restrict__ ei, int E,
                                                 const int* __restrict__ flag,
                                                 const int* __restrict__ rowp,
                                                 const int* __restrict__ rank,
                                                 IT* __restrict__ ssrc) {
    int e = blockIdx.x * 256 + threadIdx.x;
    if (e < E) {
        int f = *flag;
        int i = edst_at(ei, E, f, e);
        ssrc[rowp[i] + rank[e]] = (IT)esrc_at(ei, E, f, e);
    }
}

// ---------- dtype helpers ----------

__device__ inline void storef(float* p, size_t i, float v) { p[i] = v; }
__device__ inline void storef(__hip_bfloat16* p, size_t i, float v) {
    p[i] = __float2bfloat16(v);
}

__device__ inline void load8(const float* p, size_t row, int q, float v[8]) {
    const float4* b = reinterpret_cast<const float4*>(p + row * 64);
    float4 x = b[q * 2], y = b[q * 2 + 1];
    v[0] = x.x; v[1] = x.y; v[2] = x.z; v[3] = x.w;
    v[4] = y.x; v[5] = y.y; v[6] = y.z; v[7] = y.w;
}
__device__ inline void load8(const __hip_bfloat16* p, size_t row, int q, float v[8]) {
    uint4 u = reinterpret_cast<const uint4*>(p + row * 64)[q];
    v[0] = __uint_as_float(u.x << 16);
    v[1] = __uint_as_float(u.x & 0xffff0000u);
    v[2] = __uint_as_float(u.y << 16);
    v[3] = __uint_as_float(u.y & 0xffff0000u);
    v[4] = __uint_as_float(u.z << 16);
    v[5] = __uint_as_float(u.z & 0xffff0000u);
    v[6] = __uint_as_float(u.w << 16);
    v[7] = __uint_as_float(u.w & 0xffff0000u);
}

// ---------- lin2: W in LDS, 2 rows per lane (halves LDS-read bytes/row).
// NOTE: 4-row + fused variants measured WORSE (204 VGPR -> 6% occupancy, R9);
// register-W variant measured WORSE (180 VGPR -> 9% occupancy, R7).
template <typename ST, typename SR>
__global__ __launch_bounds__(256) void k_lin2(const float* __restrict__ x,
                                              const float* __restrict__ Wl,
                                              const float* __restrict__ bl,
                                              const float* __restrict__ Wr,
                                              const float* __restrict__ br,
                                              ST* __restrict__ xl,
                                              SR* __restrict__ xr, int n) {
    __shared__ float sWl[4096], sWr[4096], sbl[64], sbr[64];
    int t = threadIdx.x;
    for (int k = t; k < 4096; k += 256) {
        sWl[k] = Wl[k];
        sWr[k] = Wr[k];
    }
    if (t < 64) {
        sbl[t] = bl[t];
        sbr[t] = br[t];
    }
    __syncthreads();
    int col = t & 63;
    int rl = t >> 6;  // 0..3
    int noct = (n + 7) >> 3;
    for (int g = blockIdx.x; g < noct; g += gridDim.x) {
        int row0 = g * 8 + rl * 2;  // this lane's two rows
        bool ok0 = (row0 < n), ok1 = (row0 + 1 < n);
        const float* xp = x + (size_t)row0 * 64;
        float al0 = sbl[col], ar0 = sbr[col];
        float al1 = al0, ar1 = ar0;
#pragma unroll
        for (int k4 = 0; k4 < 16; ++k4) {
            float4 xv0 = ok0 ? *reinterpret_cast<const float4*>(xp + k4 * 4)
                             : make_float4(0.f, 0.f, 0.f, 0.f);
            float4 xv1 = ok1 ? *reinterpret_cast<const float4*>(xp + 64 + k4 * 4)
                             : make_float4(0.f, 0.f, 0.f, 0.f);
            int kb = k4 << 2;
            float wl0 = sWl[((kb + 0) << 6) + col], wr0 = sWr[((kb + 0) << 6) + col];
            float wl1 = sWl[((kb + 1) << 6) + col], wr1 = sWr[((kb + 1) << 6) + col];
            float wl2 = sWl[((kb + 2) << 6) + col], wr2 = sWr[((kb + 2) << 6) + col];
            float wl3 = sWl[((kb + 3) << 6) + col], wr3 = sWr[((kb + 3) << 6) + col];
            al0 = fmaf(xv0.x, wl0, al0); ar0 = fmaf(xv0.x, wr0, ar0);
            al0 = fmaf(xv0.y, wl1, al0); ar0 = fmaf(xv0.y, wr1, ar0);
            al0 = fmaf(xv0.z, wl2, al0); ar0 = fmaf(xv0.z, wr2, ar0);
            al0 = fmaf(xv0.w, wl3, al0); ar0 = fmaf(xv0.w, wr3, ar0);
            al1 = fmaf(xv1.x, wl0, al1); ar1 = fmaf(xv1.x, wr0, ar1);
            al1 = fmaf(xv1.y, wl1, al1); ar1 = fmaf(xv1.y, wr1, ar1);
            al1 = fmaf(xv1.z, wl2, al1); ar1 = fmaf(xv1.z, wr2, ar1);
            al1 = fmaf(xv1.w, wl3, al1); ar1 = fmaf(xv1.w, wr3, ar1);
        }
        if (ok0) {
            storef(xl, (size_t)row0 * 64 + col, al0);
            storef(xr, (size_t)row0 * 64 + col, ar0);
        }
        if (ok1) {
            storef(xl, (size_t)(row0 + 1) * 64 + col, al1);
            storef(xr, (size_t)(row0 + 1) * 64 + col, ar1);
        }
    }
}

// ---------- gat: one wave per node; 8 groups of 8 lanes ----------
template <typename ST, typename SR, typename IT>
__global__ __launch_bounds__(256) void k_gat(const ST* __restrict__ xl,
                                             const SR* __restrict__ xr,
                                             const int* __restrict__ rowp,
                                             const IT* __restrict__ ssrc,
                                             const float* __restrict__ att,
                                             const float* __restrict__ bias,
                                             float* __restrict__ out, int n) {
    int wid = (blockIdx.x * 256 + threadIdx.x) >> 6;
    if (wid >= n) return;
    int lane = threadIdx.x & 63;
    int g = lane >> 3;
    int q = lane & 7;
    float a[8], r[8];
    load8(att, 0, q, a);
    load8(xr, (size_t)wid, q, r);
    int beg = rowp[wid], end = rowp[wid + 1];
    float m = -3.4e38f, denom = 0.f;
    float acc[8] = {0.f, 0.f, 0.f, 0.f, 0.f, 0.f, 0.f, 0.f};
    for (int e = beg; e < end; e += 8) {
        int rem = end - e;
        bool valid = (g < rem);
        int idx = e + (valid ? g : rem - 1);
        int s = (int)ssrc[idx];
        float v[8];
        load8(xl, (size_t)s, q, v);
        float l = 0.f;
#pragma unroll
        for (int j = 0; j < 8; ++j) {
            float tj = v[j] + r[j];
            tj = tj > 0.f ? tj : SLOPE * tj;
            l = fmaf(a[j], tj, l);
        }
        l += __shfl_xor(l, 1);
        l += __shfl_xor(l, 2);
        l += __shfl_xor(l, 4);
        float mnew = valid ? fmaxf(m, l) : m;
        float sc = __expf(m - mnew);
        float p = valid ? __expf(l - mnew) : 0.f;
        denom = denom * sc + p;
#pragma unroll
        for (int j = 0; j < 8; ++j) acc[j] = fmaf(acc[j], sc, p * v[j]);
        m = mnew;
    }
    float mt = m;
    mt = fmaxf(mt, __shfl_xor(mt, 8));
    mt = fmaxf(mt, __shfl_xor(mt, 16));
    mt = fmaxf(mt, __shfl_xor(mt, 32));
    float sc = __expf(m - mt);
    denom *= sc;
    denom += __shfl_xor(denom, 8);
    denom += __shfl_xor(denom, 16);
    denom += __shfl_xor(denom, 32);
#pragma unroll
    for (int j = 0; j < 8; ++j) {
        acc[j] *= sc;
        acc[j] += __shfl_xor(acc[j], 8);
        acc[j] += __shfl_xor(acc[j], 16);
        acc[j] += __shfl_xor(acc[j], 32);
    }
    if (g == 0) {
        float b[8];
        load8(bias, 0, q, b);
        float inv = 1.f / denom;
        float o[8];
#pragma unroll
        for (int j = 0; j < 8; ++j) {
            float oj = acc[j] * inv + b[j];
            o[j] = 0.5f * oj * (1.0f + erff(oj * 0.70710678118654752f));
        }
        float4* ob = reinterpret_cast<float4*>(out + (size_t)wid * 64);
        ob[q * 2] = make_float4(o[0], o[1], o[2], o[3]);
        ob[q * 2 + 1] = make_float4(o[4], o[5], o[6], o[7]);
    }
}

// ---------- launch ----------

template <typename ST, typename SR, typename IT>
static void run_layers(const float* x0, const float* Wl, const float* bl,
                       const float* Wr, const float* br, const float* att,
                       const float* bias, ST* xl, SR* xr, const int* rowp,
                       const IT* ssrc, float* xout, int N, hipStream_t stream) {
    int gat_grid = (N + 3) / 4;
    for (int l = 0; l < 3; ++l) {
        const float* xin = (l == 0) ? x0 : xout;
        k_lin2<ST, SR><<<2048, 256, 0, stream>>>(
            xin, Wl + (size_t)l * 4096, bl + (size_t)l * 64,
            Wr + (size_t)l * 4096, br + (size_t)l * 64, xl, xr, N);
        k_gat<ST, SR, IT><<<gat_grid, 256, 0, stream>>>(xl, xr, rowp, ssrc,
                                                        att + (size_t)l * 64,
                                                        bias + (size_t)l * 64,
                                                        xout, N);
    }
}

extern "C" void kernel_launch(void* const* d_in, const int* in_sizes, int n_in,
                              void* d_out, int out_size, void* d_ws, size_t ws_size,
                              hipStream_t stream) {
    (void)n_in;
    (void)out_size;
    const float* x0 = (const float*)d_in[0];
    const int* ei = (const int*)d_in[1];
    const float* Wl = (const float*)d_in[2];
    const float* bl = (const float*)d_in[3];
    const float* Wr = (const float*)d_in[4];
    const float* br = (const float*)d_in[5];
    const float* att = (const float*)d_in[6];
    const float* bias = (const float*)d_in[7];

    int N = in_sizes[0] / 64;
    int E = in_sizes[1] / 2;
    size_t ND = (size_t)N * 64;

    char* w = (char*)d_ws;
    int* flag = (int*)w;       w += 256;
    int* parts = (int*)w;      w += 4096;
    int* rowp = (int*)w;       w += ((size_t)N + 8) * 4;
    int* deg = (int*)w;        w += ((size_t)N + 8) * 4;
    int* rank = (int*)w;       w += ((size_t)E + 8) * 4;
    unsigned short* ssrc16 = (unsigned short*)w;
    int* ssrc32 = (int*)w;     w += ((size_t)E + 8) * 4;
    size_t head = (size_t)(w - (char*)d_ws);

    bool big = (ws_size >= head + ND * 2 + ND * 4 + 4096);
    bool small_ids = (N <= 65535);

    int NB = (N + 1023) / 1024;
    int neb = (E + 255) / 256;
    int nzb = (N + 255) / 256;

    k_init<<<nzb, 256, 0, stream>>>(deg, N, ei, flag);
    k_hist<<<neb, 256, 0, stream>>>(ei, E, flag, deg, rank);
    k_scan_part<<<NB, 256, 0, stream>>>(deg, N, parts);
    k_scan_final<<<NB, 256, 0, stream>>>(deg, N, parts, NB, rowp);
    if (small_ids)
        k_scatter<unsigned short><<<neb, 256, 0, stream>>>(ei, E, flag, rowp, rank, ssrc16);
    else
        k_scatter<int><<<neb, 256, 0, stream>>>(ei, E, flag, rowp, rank, ssrc32);

    float* xout = (float*)d_out;
    if (big) {
        __hip_bfloat16* xl = (__hip_bfloat16*)w;
        float* xr = (float*)(w + ND * 2);
        if (small_ids)
            run_layers<__hip_bfloat16, float, unsigned short>(
                x0, Wl, bl, Wr, br, att, bias, xl, xr, rowp, ssrc16, xout, N, stream);
        else
            run_layers<__hip_bfloat16, float, int>(
                x0, Wl, bl, Wr, br, att, bias, xl, xr, rowp, ssrc32, xout, N, stream);
    } else {
        __hip_bfloat16* xl = (__hip_bfloat16*)w;
        __hip_bfloat16* xr = xl + ND;
        if (small_ids)
            run_layers<__hip_bfloat16, __hip_bfloat16, unsigned short>(
                x0, Wl, bl, Wr, br, att, bias, xl, xr, rowp, ssrc16, xout, N, stream);
        else
            run_layers<__hip_bfloat16, __hip_bfloat16, int>(
                x0, Wl, bl, Wr, br, att, bias, xl, xr, rowp, ssrc32, xout, N, stream);
    }
}

// Round 11
// 270.475 us; speedup vs baseline: 1.6307x; 1.3248x over previous
//
#include <hip/hip_runtime.h>
#include <hip/hip_bf16.h>

#define SLOPE 0.2f

// ---------- init: zero deg + detect edge-index dtype ----------
__global__ __launch_bounds__(256) void k_init(int* __restrict__ deg, int n,
                                              const int* __restrict__ ei,
                                              int* __restrict__ flag) {
    int i = blockIdx.x * 256 + threadIdx.x;
    if (i < n) deg[i] = 0;
    if (blockIdx.x == 0) {
        __shared__ int cnt;
        if (threadIdx.x == 0) cnt = 0;
        __syncthreads();
        int z = 0;
        for (int k = threadIdx.x; k < 4096; k += 256)
            if ((k & 1) && ei[k] == 0) z++;
        atomicAdd(&cnt, z);
        __syncthreads();
        if (threadIdx.x == 0) *flag = (cnt > 1024) ? 1 : 0;
    }
}

__device__ inline int esrc_at(const int* ei, int E, int f, int e) {
    return f ? ei[2 * e] : ei[e];
}
__device__ inline int edst_at(const int* ei, int E, int f, int e) {
    return f ? ei[2 * (E + e)] : ei[E + e];
}

// ---------- CSR build ----------

__global__ __launch_bounds__(256) void k_hist(const int* __restrict__ ei, int E,
                                              const int* __restrict__ flag,
                                              int* __restrict__ deg,
                                              int* __restrict__ rank) {
    int e = blockIdx.x * 256 + threadIdx.x;
    if (e < E) rank[e] = atomicAdd(&deg[edst_at(ei, E, *flag, e)], 1);
}

__global__ __launch_bounds__(256) void k_scan_part(const int* __restrict__ deg, int n,
                                                   int* __restrict__ parts) {
    __shared__ int s[256];
    int base = blockIdx.x * 1024;
    int sum = 0;
    for (int j = threadIdx.x; j < 1024; j += 256) {
        int i = base + j;
        sum += (i < n) ? deg[i] : 0;
    }
    s[threadIdx.x] = sum;
    __syncthreads();
    for (int off = 128; off > 0; off >>= 1) {
        if (threadIdx.x < off) s[threadIdx.x] += s[threadIdx.x + off];
        __syncthreads();
    }
    if (threadIdx.x == 0) parts[blockIdx.x] = s[0];
}

__global__ __launch_bounds__(256) void k_scan_final(const int* __restrict__ deg, int n,
                                                    const int* __restrict__ parts,
                                                    int NB, int* __restrict__ rowp) {
    __shared__ int sp[1024];
    __shared__ int s[256];
    int t = threadIdx.x;
    for (int j = t; j < 1024; j += 256) sp[j] = (j < NB) ? parts[j] : 0;
    __syncthreads();
    for (int off = 1; off < 1024; off <<= 1) {
        int v[4];
        for (int c = 0; c < 4; ++c) {
            int j = t + c * 256;
            v[c] = (j >= off) ? sp[j - off] : 0;
        }
        __syncthreads();
        for (int c = 0; c < 4; ++c) sp[t + c * 256] += v[c];
        __syncthreads();
    }
    int b = blockIdx.x;
    int chunk_off = (b == 0) ? 0 : sp[b - 1];
    if (b == 0 && t == 0) rowp[n] = sp[NB - 1];
    int base = b * 1024 + t * 4;
    int v0 = (base + 0 < n) ? deg[base + 0] : 0;
    int v1 = (base + 1 < n) ? deg[base + 1] : 0;
    int v2 = (base + 2 < n) ? deg[base + 2] : 0;
    int v3 = (base + 3 < n) ? deg[base + 3] : 0;
    int mysum = v0 + v1 + v2 + v3;
    s[t] = mysum;
    __syncthreads();
    for (int off = 1; off < 256; off <<= 1) {
        int add = (t >= off) ? s[t - off] : 0;
        __syncthreads();
        s[t] += add;
        __syncthreads();
    }
    int excl = chunk_off + s[t] - mysum;
    if (base + 0 < n) rowp[base + 0] = excl;
    if (base + 1 < n) rowp[base + 1] = excl + v0;
    if (base + 2 < n) rowp[base + 2] = excl + v0 + v1;
    if (base + 3 < n) rowp[base + 3] = excl + v0 + v1 + v2;
}

// atomic-free scatter: position = rowp[dst] + rank[e]
template <typename IT>
__global__ __launch_bounds__(256) void k_scatter(const int* __restrict__ ei, int E,
                                                 const int* __restrict__ flag,
                                                 const int* __restrict__ rowp,
                                                 const int* __restrict__ rank,
                                                 IT* __restrict__ ssrc) {
    int e = blockIdx.x * 256 + threadIdx.x;
    if (e < E) {
        int f = *flag;
        int i = edst_at(ei, E, f, e);
        ssrc[rowp[i] + rank[e]] = (IT)esrc_at(ei, E, f, e);
    }
}

// ---------- dtype helpers ----------

__device__ inline void storef(float* p, size_t i, float v) { p[i] = v; }
__device__ inline void storef(__hip_bfloat16* p, size_t i, float v) {
    p[i] = __float2bfloat16(v);
}

__device__ inline void load8(const float* p, size_t row, int q, float v[8]) {
    const float4* b = reinterpret_cast<const float4*>(p + row * 64);
    float4 x = b[q * 2], y = b[q * 2 + 1];
    v[0] = x.x; v[1] = x.y; v[2] = x.z; v[3] = x.w;
    v[4] = y.x; v[5] = y.y; v[6] = y.z; v[7] = y.w;
}
__device__ inline void load8(const __hip_bfloat16* p, size_t row, int q, float v[8]) {
    uint4 u = reinterpret_cast<const uint4*>(p + row * 64)[q];
    v[0] = __uint_as_float(u.x << 16);
    v[1] = __uint_as_float(u.x & 0xffff0000u);
    v[2] = __uint_as_float(u.y << 16);
    v[3] = __uint_as_float(u.y & 0xffff0000u);
    v[4] = __uint_as_float(u.z << 16);
    v[5] = __uint_as_float(u.z & 0xffff0000u);
    v[6] = __uint_as_float(u.w << 16);
    v[7] = __uint_as_float(u.w & 0xffff0000u);
}

// ---------- per-layer kernels ----------

// xl = x@Wl + bl ; xr = x@Wr + br  (D = 64), W staged in LDS, 1 row per lane.
// MEASURED LAW (R7/R9/R10): every W-reuse variant (register-W 180 VGPR,
// 4-row 204 VGPR, 2-row 136 VGPR) drops occupancy to <10% and runs ~5x
// SLOWER. The unrolled K-loop's hoisted loads multiply live ranges.
// Keep this 1-row / high-occupancy form.
template <typename ST, typename SR>
__global__ __launch_bounds__(256) void k_lin2(const float* __restrict__ x,
                                              const float* __restrict__ Wl,
                                              const float* __restrict__ bl,
                                              const float* __restrict__ Wr,
                                              const float* __restrict__ br,
                                              ST* __restrict__ xl,
                                              SR* __restrict__ xr, int n) {
    __shared__ float sWl[4096], sWr[4096], sbl[64], sbr[64];
    int t = threadIdx.x;
    for (int k = t; k < 4096; k += 256) {
        sWl[k] = Wl[k];
        sWr[k] = Wr[k];
    }
    if (t < 64) {
        sbl[t] = bl[t];
        sbr[t] = br[t];
    }
    __syncthreads();
    int col = t & 63;
    int rl = t >> 6;
    int ngroups = (n + 3) >> 2;
    for (int g = blockIdx.x; g < ngroups; g += gridDim.x) {
        int row = g * 4 + rl;
        if (row < n) {
            const float4* xp4 = reinterpret_cast<const float4*>(x + (size_t)row * 64);
            float al = sbl[col], ar = sbr[col];
#pragma unroll
            for (int k4 = 0; k4 < 16; ++k4) {
                float4 xv = xp4[k4];
                int kb = k4 << 2;
                al = fmaf(xv.x, sWl[((kb + 0) << 6) + col], al);
                ar = fmaf(xv.x, sWr[((kb + 0) << 6) + col], ar);
                al = fmaf(xv.y, sWl[((kb + 1) << 6) + col], al);
                ar = fmaf(xv.y, sWr[((kb + 1) << 6) + col], ar);
                al = fmaf(xv.z, sWl[((kb + 2) << 6) + col], al);
                ar = fmaf(xv.z, sWr[((kb + 2) << 6) + col], ar);
                al = fmaf(xv.w, sWl[((kb + 3) << 6) + col], al);
                ar = fmaf(xv.w, sWr[((kb + 3) << 6) + col], ar);
            }
            storef(xl, (size_t)row * 64 + col, al);
            storef(xr, (size_t)row * 64 + col, ar);
        }
    }
}

// one wave per node; 8 groups of 8 lanes, each group owns one edge slot;
// lane holds 8 dims. Per-group branchless online softmax, merged at the end.
template <typename ST, typename SR, typename IT>
__global__ __launch_bounds__(256) void k_gat(const ST* __restrict__ xl,
                                             const SR* __restrict__ xr,
                                             const int* __restrict__ rowp,
                                             const IT* __restrict__ ssrc,
                                             const float* __restrict__ att,
                                             const float* __restrict__ bias,
                                             float* __restrict__ out, int n) {
    int wid = (blockIdx.x * 256 + threadIdx.x) >> 6;
    if (wid >= n) return;
    int lane = threadIdx.x & 63;
    int g = lane >> 3;
    int q = lane & 7;
    float a[8], r[8];
    load8(att, 0, q, a);
    load8(xr, (size_t)wid, q, r);
    int beg = rowp[wid], end = rowp[wid + 1];
    float m = -3.4e38f, denom = 0.f;
    float acc[8] = {0.f, 0.f, 0.f, 0.f, 0.f, 0.f, 0.f, 0.f};
    for (int e = beg; e < end; e += 8) {
        int rem = end - e;
        bool valid = (g < rem);
        int idx = e + (valid ? g : rem - 1);
        int s = (int)ssrc[idx];
        float v[8];
        load8(xl, (size_t)s, q, v);
        float l = 0.f;
#pragma unroll
        for (int j = 0; j < 8; ++j) {
            float tj = v[j] + r[j];
            tj = tj > 0.f ? tj : SLOPE * tj;
            l = fmaf(a[j], tj, l);
        }
        l += __shfl_xor(l, 1);
        l += __shfl_xor(l, 2);
        l += __shfl_xor(l, 4);
        float mnew = valid ? fmaxf(m, l) : m;
        float sc = __expf(m - mnew);
        float p = valid ? __expf(l - mnew) : 0.f;
        denom = denom * sc + p;
#pragma unroll
        for (int j = 0; j < 8; ++j) acc[j] = fmaf(acc[j], sc, p * v[j]);
        m = mnew;
    }
    float mt = m;
    mt = fmaxf(mt, __shfl_xor(mt, 8));
    mt = fmaxf(mt, __shfl_xor(mt, 16));
    mt = fmaxf(mt, __shfl_xor(mt, 32));
    float sc = __expf(m - mt);
    denom *= sc;
    denom += __shfl_xor(denom, 8);
    denom += __shfl_xor(denom, 16);
    denom += __shfl_xor(denom, 32);
#pragma unroll
    for (int j = 0; j < 8; ++j) {
        acc[j] *= sc;
        acc[j] += __shfl_xor(acc[j], 8);
        acc[j] += __shfl_xor(acc[j], 16);
        acc[j] += __shfl_xor(acc[j], 32);
    }
    if (g == 0) {
        float b[8];
        load8(bias, 0, q, b);
        float inv = 1.f / denom;
        float o[8];
#pragma unroll
        for (int j = 0; j < 8; ++j) {
            float oj = acc[j] * inv + b[j];
            o[j] = 0.5f * oj * (1.0f + erff(oj * 0.70710678118654752f));
        }
        float4* ob = reinterpret_cast<float4*>(out + (size_t)wid * 64);
        ob[q * 2] = make_float4(o[0], o[1], o[2], o[3]);
        ob[q * 2 + 1] = make_float4(o[4], o[5], o[6], o[7]);
    }
}

// ---------- launch ----------

template <typename ST, typename SR, typename IT>
static void run_layers(const float* x0, const float* Wl, const float* bl,
                       const float* Wr, const float* br, const float* att,
                       const float* bias, ST* xl, SR* xr, const int* rowp,
                       const IT* ssrc, float* xout, int N, hipStream_t stream) {
    int gat_grid = (N + 3) / 4;
    for (int l = 0; l < 3; ++l) {
        const float* xin = (l == 0) ? x0 : xout;
        k_lin2<ST, SR><<<2048, 256, 0, stream>>>(
            xin, Wl + (size_t)l * 4096, bl + (size_t)l * 64,
            Wr + (size_t)l * 4096, br + (size_t)l * 64, xl, xr, N);
        k_gat<ST, SR, IT><<<gat_grid, 256, 0, stream>>>(xl, xr, rowp, ssrc,
                                                        att + (size_t)l * 64,
                                                        bias + (size_t)l * 64,
                                                        xout, N);
    }
}

extern "C" void kernel_launch(void* const* d_in, const int* in_sizes, int n_in,
                              void* d_out, int out_size, void* d_ws, size_t ws_size,
                              hipStream_t stream) {
    (void)n_in;
    (void)out_size;
    const float* x0 = (const float*)d_in[0];
    const int* ei = (const int*)d_in[1];
    const float* Wl = (const float*)d_in[2];
    const float* bl = (const float*)d_in[3];
    const float* Wr = (const float*)d_in[4];
    const float* br = (const float*)d_in[5];
    const float* att = (const float*)d_in[6];
    const float* bias = (const float*)d_in[7];

    int N = in_sizes[0] / 64;
    int E = in_sizes[1] / 2;
    size_t ND = (size_t)N * 64;

    char* w = (char*)d_ws;
    int* flag = (int*)w;       w += 256;
    int* parts = (int*)w;      w += 4096;
    int* rowp = (int*)w;       w += ((size_t)N + 8) * 4;
    int* deg = (int*)w;        w += ((size_t)N + 8) * 4;
    int* rank = (int*)w;       w += ((size_t)E + 8) * 4;
    unsigned short* ssrc16 = (unsigned short*)w;
    int* ssrc32 = (int*)w;     w += ((size_t)E + 8) * 4;
    size_t head = (size_t)(w - (char*)d_ws);

    bool big = (ws_size >= head + ND * 2 + ND * 4 + 4096);
    bool small_ids = (N <= 65535);

    int NB = (N + 1023) / 1024;
    int neb = (E + 255) / 256;
    int nzb = (N + 255) / 256;

    k_init<<<nzb, 256, 0, stream>>>(deg, N, ei, flag);
    k_hist<<<neb, 256, 0, stream>>>(ei, E, flag, deg, rank);
    k_scan_part<<<NB, 256, 0, stream>>>(deg, N, parts);
    k_scan_final<<<NB, 256, 0, stream>>>(deg, N, parts, NB, rowp);
    if (small_ids)
        k_scatter<unsigned short><<<neb, 256, 0, stream>>>(ei, E, flag, rowp, rank, ssrc16);
    else
        k_scatter<int><<<neb, 256, 0, stream>>>(ei, E, flag, rowp, rank, ssrc32);

    float* xout = (float*)d_out;
    if (big) {
        __hip_bfloat16* xl = (__hip_bfloat16*)w;
        float* xr = (float*)(w + ND * 2);
        if (small_ids)
            run_layers<__hip_bfloat16, float, unsigned short>(
                x0, Wl, bl, Wr, br, att, bias, xl, xr, rowp, ssrc16, xout, N, stream);
        else
            run_layers<__hip_bfloat16, float, int>(
                x0, Wl, bl, Wr, br, att, bias, xl, xr, rowp, ssrc32, xout, N, stream);
    } else {
        __hip_bfloat16* xl = (__hip_bfloat16*)w;
        __hip_bfloat16* xr = xl + ND;
        if (small_ids)
            run_layers<__hip_bfloat16, __hip_bfloat16, unsigned short>(
                x0, Wl, bl, Wr, br, att, bias, xl, xr, rowp, ssrc16, xout, N, stream);
        else
            run_layers<__hip_bfloat16, __hip_bfloat16, int>(
                x0, Wl, bl, Wr, br, att, bias, xl, xr, rowp, ssrc32, xout, N, stream);
    }
}